// Round 8
// baseline (646.220 us; speedup 1.0000x reference)
//
#include <hip/hip_runtime.h>
#include <cstdint>
#include <cstddef>

typedef __attribute__((ext_vector_type(4))) float f32x4;
typedef __attribute__((ext_vector_type(8))) __bf16 bf16x8;
typedef __attribute__((ext_vector_type(4))) unsigned int u32x4;
typedef __attribute__((ext_vector_type(2))) unsigned int u32x2;

#define DEVFN static __device__ __forceinline__
#define AGENT __HIP_MEMORY_SCOPE_AGENT

// ---------------- workspace layout (bytes) ----------------
#define OFF_XBF    0ull                 // bf16 x        8192x1024  (16MB)
#define OFF_WINBF  16777216ull          // bf16 W_in[0:2048] 2048x1024 (4MB)
#define OFF_WXBF   20971520ull          // bf16 W_x      32x2048
#define OFF_WOUTBF 21102592ull          // bf16 W_out    1024x2048  (4MB)
#define OFF_WRT    25296896ull          // bf16 Wr^T     1024x2048  (4MB) [k][d]
#define OFF_WC     29491200ull          // bf16 Wc       1024x1024  (2MB) [m][k]
#define OFF_WRED   31588352ull          // f32  W_red    1024x16
#define OFF_BCONST 31653888ull          // f32  bconst   1024
#define OFF_XIBF   31657984ull          // bf16 xi       8192x2048  (32MB)
#define OFF_BC     98766848ull          // f32  bc       8192x32    (1MB)
#define OFF_HS     99815424ull          // f32  hs       8192x16    (512KB)
#define OFF_FLAGS  100339712ull         // int  cnt1[64], flag2[64]

DEVFN unsigned short f2bf(float f) {
  unsigned u = __float_as_uint(f);
  return (unsigned short)((u + 0x7FFFu + ((u >> 16) & 1u)) >> 16);
}

DEVFN void gload_lds16(const void* g, void* l) {
  __builtin_amdgcn_global_load_lds(
      (const __attribute__((address_space(1))) void*)g,
      (__attribute__((address_space(3))) void*)l, 16, 0, 0);
}

// DPP quad_perm: 0xB1=[1,0,3,2](xor1), 0x4E=[2,3,0,1](xor2)
#define DPPF(x, ctrl) \
  __int_as_float(__builtin_amdgcn_update_dpp(0, __float_as_int(x), ctrl, 0xF, 0xF, true))

// ---------------- prep: converts + W_red + bconst + Wr-transpose ------------
DEVFN void cvt8(const float* __restrict__ in, unsigned short* __restrict__ out, int t) {
  f32x4 a = *(const f32x4*)(in + (size_t)t * 8);
  f32x4 b = *(const f32x4*)(in + (size_t)t * 8 + 4);
  u32x4 r;
  r.x = (unsigned)f2bf(a[0]) | ((unsigned)f2bf(a[1]) << 16);
  r.y = (unsigned)f2bf(a[2]) | ((unsigned)f2bf(a[3]) << 16);
  r.z = (unsigned)f2bf(b[0]) | ((unsigned)f2bf(b[1]) << 16);
  r.w = (unsigned)f2bf(b[2]) | ((unsigned)f2bf(b[3]) << 16);
  *(u32x4*)(out + (size_t)t * 8) = r;
}

__global__ __launch_bounds__(256) void k_prep(
    const float* __restrict__ x, const float* __restrict__ W_in,
    const float* __restrict__ W_x, const float* __restrict__ W_out,
    const float* __restrict__ b_in, const float* __restrict__ b_out,
    unsigned short* __restrict__ xbf, unsigned short* __restrict__ winbf,
    unsigned short* __restrict__ wxbf, unsigned short* __restrict__ woutbf,
    unsigned short* __restrict__ wrtbf, float* __restrict__ wred,
    float* __restrict__ bconst) {
  const int bid = blockIdx.x, tid = threadIdx.x;
  if (bid < 4096)      { cvt8(x,     xbf,    bid * 256 + tid); return; }
  if (bid < 5120)      { cvt8(W_in,  winbf,  (bid - 4096) * 256 + tid); return; }
  if (bid < 5152)      { cvt8(W_x,   wxbf,   (bid - 5120) * 256 + tid); return; }
  if (bid < 6176)      { cvt8(W_out, woutbf, (bid - 5152) * 256 + tid); return; }
  if (bid < 6240) {
    // W_red[m][j] = sum_{r<128} W_out[m][r*16+j]
    const int t = (bid - 6176) * 256 + tid;
    const int m = t >> 4, j = t & 15;
    float s = 0.f;
    for (int r = 0; r < 128; r++) s += W_out[(size_t)m * 2048 + r * 16 + j];
    wred[t] = s;
    return;
  }
  if (bid < 6256) {
    // bconst[m] = b_out[m] + sum_d W_out[m][d]*b_in[2048+d]
    const int t = (bid - 6240) * 256 + tid;
    const int m = t >> 2, q = t & 3;
    const float* wr = W_out + (size_t)m * 2048 + q * 512;
    const float* bi = b_in + 2048 + q * 512;
    float s = 0.f;
    for (int j = 0; j < 128; j++) {
      const f32x4 w = *(const f32x4*)(wr + j * 4);
      const f32x4 v = *(const f32x4*)(bi + j * 4);
      s += w[0]*v[0] + w[1]*v[1] + w[2]*v[2] + w[3]*v[3];
    }
    s += DPPF(s, 0xB1);
    s += DPPF(s, 0x4E);
    if ((tid & 3) == 0) bconst[m] = b_out[m] + s;
    return;
  }
  // transpose-convert: wrt[k][d] = (bf16) W_in[2048+d][k]; 64x64 tiles
  __shared__ float lt[64][65];
  const int tt = bid - 6256;                 // 512 tiles: 32 d-tiles x 16 k-tiles
  const int d0 = (tt >> 4) * 64, k0 = (tt & 15) * 64;
  const int r16 = tid >> 4, c4 = tid & 15;
#pragma unroll
  for (int i = 0; i < 4; i++) {
    const int dr = r16 + i * 16;
    const f32x4 v = *(const f32x4*)(W_in + (size_t)(2048 + d0 + dr) * 1024 + k0 + c4 * 4);
    lt[dr][c4 * 4 + 0] = v[0]; lt[dr][c4 * 4 + 1] = v[1];
    lt[dr][c4 * 4 + 2] = v[2]; lt[dr][c4 * 4 + 3] = v[3];
  }
  __syncthreads();
#pragma unroll
  for (int i = 0; i < 4; i++) {
    const int kr = r16 + i * 16;
    u32x2 rr;
    rr.x = (unsigned)f2bf(lt[c4 * 4 + 0][kr]) | ((unsigned)f2bf(lt[c4 * 4 + 1][kr]) << 16);
    rr.y = (unsigned)f2bf(lt[c4 * 4 + 2][kr]) | ((unsigned)f2bf(lt[c4 * 4 + 3][kr]) << 16);
    *(u32x2*)(wrtbf + (size_t)(k0 + kr) * 2048 + d0 + c4 * 4) = rr;
  }
}

// ---------------- bf16 NT MFMA GEMM core (shared-buffer parameterized) ------
// 128x128 tile, BK=64, 4 waves, linear LDS, global_load_lds w=16 (m97).
// EPI 0: bf16 out stride 2048, +bias (xi). EPI 1: f32 out stride 1024, +bias.
// EPI 2: bf16 out stride 1024, no bias (Wc).
template <int EPI>
DEVFN void gemm128(unsigned short* __restrict__ As, unsigned short* __restrict__ Bs,
                   const unsigned short* __restrict__ Ag,
                   const unsigned short* __restrict__ Bg, int K,
                   int m0, int n0, const float* __restrict__ bias,
                   float* __restrict__ outf, unsigned short* __restrict__ outbf) {
  const int tid = threadIdx.x;
  const int wave = tid >> 6, lane = tid & 63;
  const int wm = wave >> 1, wn = wave & 1;
  const int fr = lane & 15;
  const int k8 = (lane >> 4) << 3;

  f32x4 acc[4][4];
#pragma unroll
  for (int a = 0; a < 4; a++)
#pragma unroll
    for (int b = 0; b < 4; b++) acc[a][b] = f32x4{0.f, 0.f, 0.f, 0.f};

  for (int kt = 0; kt < K; kt += 64) {
#pragma unroll
    for (int i = 0; i < 4; i++) {
      const int base = (wave << 10) + (i << 12);
      const int off = base + (lane << 4);
      const int row = off >> 7;
      const int col = (off & 127) >> 1;
      gload_lds16(Ag + (size_t)(m0 + row) * K + kt + col, (char*)As + base);
      gload_lds16(Bg + (size_t)(n0 + row) * K + kt + col, (char*)Bs + base);
    }
    __syncthreads();
#pragma unroll
    for (int kk = 0; kk < 2; kk++) {
      bf16x8 af[4], bfr[4];
#pragma unroll
      for (int f = 0; f < 4; f++) {
        af[f]  = *(const bf16x8*)&As[(wm * 64 + f * 16 + fr) * 64 + kk * 32 + k8];
        bfr[f] = *(const bf16x8*)&Bs[(wn * 64 + f * 16 + fr) * 64 + kk * 32 + k8];
      }
#pragma unroll
      for (int fi = 0; fi < 4; fi++)
#pragma unroll
        for (int fj = 0; fj < 4; fj++)
          acc[fi][fj] = __builtin_amdgcn_mfma_f32_16x16x32_bf16(
              af[fi], bfr[fj], acc[fi][fj], 0, 0, 0);
    }
    __syncthreads();
  }

  const int r0 = (lane >> 4) * 4;
#pragma unroll
  for (int fj = 0; fj < 4; fj++) {
    const int col = n0 + wn * 64 + fj * 16 + fr;
    const float bia = (EPI == 2) ? 0.f : bias[col];
#pragma unroll
    for (int fi = 0; fi < 4; fi++) {
      const int rowb = m0 + wm * 64 + fi * 16 + r0;
#pragma unroll
      for (int r = 0; r < 4; r++) {
        const float v = acc[fi][fj][r] + bia;
        if (EPI == 0)      outbf[(size_t)(rowb + r) * 2048 + col] = f2bf(v);
        else if (EPI == 1) outf[(size_t)(rowb + r) * 1024 + col] = v;
        else               outbf[(size_t)(rowb + r) * 1024 + col] = f2bf(v);
      }
    }
  }
}

// K_wc: Wc[m][k] = sum_d W_out[m][d] * Wr^T[k][d]   (1024x1024x2048)
__global__ __launch_bounds__(256) void k_wc(const unsigned short* __restrict__ woutbf,
                                            const unsigned short* __restrict__ wrtbf,
                                            unsigned short* __restrict__ wcbf) {
  __shared__ unsigned short sm[128 * 64 * 2];
  const int bid = blockIdx.x;                // 8 x 8 tiles
  gemm128<2>(sm, sm + 128 * 64, woutbf, wrtbf, 2048,
             (bid >> 3) * 128, (bid & 7) * 128, nullptr, nullptr, wcbf);
}

// ---------------- scan step (4 lanes per state, r5 measured-best) ----------
DEVFN float scan4_step(float h, const f32x4 ax, float Bt, float Ct, int a0) {
  const int hv = __float_as_int(h);
  const float g0 = __int_as_float(__builtin_amdgcn_ds_bpermute(a0,      hv));
  const float g1 = __int_as_float(__builtin_amdgcn_ds_bpermute(a0 + 16, hv));
  const float g2 = __int_as_float(__builtin_amdgcn_ds_bpermute(a0 + 32, hv));
  const float g3 = __int_as_float(__builtin_amdgcn_ds_bpermute(a0 + 48, hv));
  const float pa = fmaf(ax[1], g1, ax[0] * g0);
  const float pb = fmaf(ax[3], g3, ax[2] * g2);
  float p = pa + pb;
  p += DPPF(p, 0xB1);
  p += DPPF(p, 0x4E);
  const float s = p + fmaf(Bt, h, Ct);
  const float e = __expf(2.f * s);
  return fmaf(-2.f, __builtin_amdgcn_rcpf(e + 1.f), 1.f);
}

// ================= MEGA kernel: gemm1 | gemm2+conv | scan | out-gemm ========
// Producer->consumer via device-scope acquire/release flags. Only gemm2 (64)
// and scan (1) blocks ever wait; producers never wait => deadlock-free under
// any dispatch order (waiters << residency capacity; worst case serializes).
__global__ __launch_bounds__(256) void k_mega(
    const unsigned short* __restrict__ xbf, const unsigned short* __restrict__ winbf,
    const float* __restrict__ b_in, unsigned short* __restrict__ xibf,
    const float* __restrict__ cw, const float* __restrict__ cb,
    const unsigned short* __restrict__ wx, const float* __restrict__ bx,
    float* __restrict__ bcb,
    const unsigned short* __restrict__ wcbf, const float* __restrict__ bconst,
    float* __restrict__ out,
    const float* __restrict__ dt, const float* __restrict__ Amat,
    float* __restrict__ hs,
    int* __restrict__ cnt1, int* __restrict__ flag2) {
  __shared__ unsigned short sm[128 * 64 * 2];   // 32KB, shared by all roles
  const int bid = blockIdx.x, tid = threadIdx.x;

  if (bid < 1024) {
    // ---- role gemm1: xi = x @ W_in[0:2048]^T + b_in  (64 m-tiles x 16 n)
    const int m = bid >> 4, n = bid & 15;
    gemm128<0>(sm, sm + 128 * 64, xbf, winbf, 1024, m * 128, n * 128,
               b_in, nullptr, xibf);
    __syncthreads();
    if (tid == 0)
      __hip_atomic_fetch_add(&cnt1[m], 1, __ATOMIC_RELEASE, AGENT);
    return;
  }

  if (bid < 1088) {
    // ---- role gemm2 + fused conv/silu A-staging: bc = silu(conv(xi)) @ W_x^T + b_x
    unsigned short* As = sm;               // 16KB [128][64]
    unsigned short* Bs = sm + 128 * 64;    // 4KB  [32][64]
    const int m = bid - 1024;              // 0..63
    const int lt = m & 15;
    const int m0 = m * 128;
    // wait for xi rows m0-3 .. m0+127 (tiles m and m-1, all 16 n-blocks)
    while (__hip_atomic_load(&cnt1[m], __ATOMIC_ACQUIRE, AGENT) < 16)
      __builtin_amdgcn_s_sleep(2);
    if (lt != 0)
      while (__hip_atomic_load(&cnt1[m - 1], __ATOMIC_ACQUIRE, AGENT) < 16)
        __builtin_amdgcn_s_sleep(2);

    const int wave = tid >> 6, lane = tid & 63;
    const int fr = lane & 15, k8 = (lane >> 4) << 3;
    f32x4 acc[2][2];
#pragma unroll
    for (int a = 0; a < 2; a++)
#pragma unroll
      for (int b = 0; b < 2; b++) acc[a][b] = f32x4{0.f, 0.f, 0.f, 0.f};

    for (int kt = 0; kt < 2048; kt += 64) {
      // B stage (global_load_lds)
      {
        const int base = (wave << 10);
        const int off = base + (lane << 4);
        const int row = off >> 7, col = (off & 127) >> 1;
        gload_lds16(wx + (size_t)row * 2048 + kt + col, (char*)Bs + base);
      }
      // A stage: compute silu(conv(xi)) for tile [128 rows][64 ch] -> As
#pragma unroll
      for (int i = 0; i < 4; i++) {
        const int off = i * 4096 + tid * 16;          // byte offset in As
        const int row = off >> 7;                     // 0..127
        const int c8 = (off & 127) >> 1;              // bf16 col, 8-wide
        const int ch = kt + c8;                       // channel base
        const size_t gb = (size_t)(m0 + row) * 2048 + ch;
        const int l = (m0 + row) & 2047;
        u32x4 raw[4];
#pragma unroll
        for (int t = 0; t < 4; t++) {
          const int lsrc = l - 3 + t;
          raw[t] = (lsrc >= 0) ? *(const u32x4*)(xibf + gb + ((long)t - 3) * 2048)
                               : u32x4{0u, 0u, 0u, 0u};
        }
        u32x4 res;
        unsigned tmp[4];
#pragma unroll
        for (int c = 0; c < 8; c++) {
          const f32x4 wv = *(const f32x4*)(cw + (size_t)(ch + c) * 4);
          float a2 = cb[ch + c];
#pragma unroll
          for (int t = 0; t < 4; t++) {
            const unsigned w32 = raw[t][c >> 1];
            const float xv = __uint_as_float((c & 1) ? (w32 & 0xFFFF0000u) : (w32 << 16));
            a2 = fmaf(wv[t], xv, a2);
          }
          const float sl = a2 * __builtin_amdgcn_rcpf(1.f + __expf(-a2));
          const unsigned hb = f2bf(sl);
          if ((c & 1) == 0) tmp[c >> 1] = hb;
          else              tmp[c >> 1] |= (hb << 16);
        }
        res.x = tmp[0]; res.y = tmp[1]; res.z = tmp[2]; res.w = tmp[3];
        *(u32x4*)((char*)As + off) = res;
      }
      __syncthreads();
#pragma unroll
      for (int kk = 0; kk < 2; kk++) {
        bf16x8 af[2], bfr[2];
#pragma unroll
        for (int f = 0; f < 2; f++) {
          af[f]  = *(const bf16x8*)&As[(wave * 32 + f * 16 + fr) * 64 + kk * 32 + k8];
          bfr[f] = *(const bf16x8*)&Bs[(f * 16 + fr) * 64 + kk * 32 + k8];
        }
#pragma unroll
        for (int fi = 0; fi < 2; fi++)
#pragma unroll
          for (int fj = 0; fj < 2; fj++)
            acc[fi][fj] = __builtin_amdgcn_mfma_f32_16x16x32_bf16(
                af[fi], bfr[fj], acc[fi][fj], 0, 0, 0);
      }
      __syncthreads();
    }
    const int r0 = (lane >> 4) * 4;
#pragma unroll
    for (int fi = 0; fi < 2; fi++)
#pragma unroll
      for (int fj = 0; fj < 2; fj++) {
        const int col = fj * 16 + fr;
        const float bia = bx[col];
#pragma unroll
        for (int r = 0; r < 4; r++) {
          const int row = m0 + wave * 32 + fi * 16 + r0 + r;
          bcb[(size_t)row * 32 + col] = acc[fi][fj][r] + bia;
        }
      }
    __syncthreads();
    if (tid == 0)
      __hip_atomic_store(&flag2[m], 1, __ATOMIC_RELEASE, AGENT);
    return;
  }

  if (bid == 1088) {
    // ---- role scan: 4 waves, wave b scans batch b, chasing gemm2 tiles
    const int b = tid >> 6;
    const int lane = tid & 63;
    const int i = lane >> 2, k = lane & 3;
    const f32x4 arow = *(const f32x4*)(Amat + i * 16 + k * 4);
    f32x4 axv[16];
#pragma unroll
    for (int p = 0; p < 16; p++) {
      const float e = __expf(dt[p]);
      axv[p][0] = __expf(e * arow[0]);
      axv[p][1] = __expf(e * arow[1]);
      axv[p][2] = __expf(e * arow[2]);
      axv[p][3] = __expf(e * arow[3]);
    }
    const int a0 = (lane & 3) << 6;
    const float* bcp = bcb + (size_t)b * 65536 + i;
    float* hsp = hs + (size_t)b * 32768 + i;
    float h = 0.f;
    float pB0[8], pC0[8], pB1[8], pC1[8];

    for (int c = 0; c < 16; ++c) {
      const int fidx = (b << 4) + c;
      while (__hip_atomic_load(&flag2[fidx], __ATOMIC_ACQUIRE, AGENT) == 0)
        __builtin_amdgcn_s_sleep(2);
      const int base = c << 7;
      {
        const float* bq = bcp + (size_t)base * 32;
#pragma unroll
        for (int q = 0; q < 8; q++) { pB0[q] = bq[q * 32]; pC0[q] = bq[q * 32 + 16]; }
      }
      for (int g = 0; g < 8; ++g) {
        const int l0 = base + (g << 4);
        {
          const float* bq = bcp + (size_t)(l0 + 8) * 32;
#pragma unroll
          for (int q = 0; q < 8; q++) { pB1[q] = bq[q * 32]; pC1[q] = bq[q * 32 + 16]; }
        }
#pragma unroll
        for (int q = 0; q < 8; q++) {
          h = scan4_step(h, axv[q], pB0[q], pC0[q], a0);
          if (k == 0) hsp[(size_t)(l0 + q) * 16] = h;
        }
        if (g < 7) {
          const float* bq = bcp + (size_t)(l0 + 16) * 32;
#pragma unroll
          for (int q = 0; q < 8; q++) { pB0[q] = bq[q * 32]; pC0[q] = bq[q * 32 + 16]; }
        }
#pragma unroll
        for (int q = 0; q < 8; q++) {
          h = scan4_step(h, axv[8 + q], pB1[q], pC1[q], a0);
          if (k == 0) hsp[(size_t)(l0 + 8 + q) * 16] = h;
        }
      }
    }
    return;
  }

  // ---- role out-gemm: out = x @ Wc^T + bconst   (64 x 8 tiles)
  {
    const int bid2 = bid - 1089;
    gemm128<1>(sm, sm + 128 * 64, xbf, wcbf, 1024,
               (bid2 >> 3) * 128, (bid2 & 7) * 128, bconst, out, nullptr);
  }
}

// K5: out += hs @ W_red^T
__global__ __launch_bounds__(256) void k5_combine(float* __restrict__ out,
                                                  const float* __restrict__ hs,
                                                  const float* __restrict__ wred) {
  const int m4 = threadIdx.x;
  const int rg = blockIdx.x;
  f32x4 w[4][4];
#pragma unroll
  for (int mi = 0; mi < 4; mi++)
#pragma unroll
    for (int q = 0; q < 4; q++)
      w[mi][q] = *(const f32x4*)&wred[(size_t)(m4 * 4 + mi) * 16 + q * 4];
#pragma unroll
  for (int r = 0; r < 4; r++) {
    const size_t row = (size_t)rg * 4 + r;
    f32x4 hv[4];
#pragma unroll
    for (int q = 0; q < 4; q++) hv[q] = *(const f32x4*)&hs[row * 16 + q * 4];
    float* op = out + row * 1024 + m4 * 4;
    f32x4 o = *(f32x4*)op;
#pragma unroll
    for (int mi = 0; mi < 4; mi++) {
      float v = 0.f;
#pragma unroll
      for (int q = 0; q < 4; q++)
        v += w[mi][q][0]*hv[q][0] + w[mi][q][1]*hv[q][1] +
             w[mi][q][2]*hv[q][2] + w[mi][q][3]*hv[q][3];
      o[mi] += v;
    }
    *(f32x4*)op = o;
  }
}

extern "C" void kernel_launch(void* const* d_in, const int* in_sizes, int n_in,
                              void* d_out, int out_size, void* d_ws, size_t ws_size,
                              hipStream_t stream) {
  const float* x      = (const float*)d_in[0];
  const float* W_in   = (const float*)d_in[1];
  const float* b_in   = (const float*)d_in[2];
  const float* conv_w = (const float*)d_in[3];
  const float* conv_b = (const float*)d_in[4];
  const float* W_x    = (const float*)d_in[5];
  const float* b_x    = (const float*)d_in[6];
  const float* dt     = (const float*)d_in[7];
  const float* A      = (const float*)d_in[8];
  const float* W_out  = (const float*)d_in[10];
  const float* b_out  = (const float*)d_in[11];
  float* out = (float*)d_out;

  char* ws = (char*)d_ws;
  unsigned short* xbf    = (unsigned short*)(ws + OFF_XBF);
  unsigned short* winbf  = (unsigned short*)(ws + OFF_WINBF);
  unsigned short* wxbf   = (unsigned short*)(ws + OFF_WXBF);
  unsigned short* woutbf = (unsigned short*)(ws + OFF_WOUTBF);
  unsigned short* wrtbf  = (unsigned short*)(ws + OFF_WRT);
  unsigned short* wcbf   = (unsigned short*)(ws + OFF_WC);
  float*          wred   = (float*)(ws + OFF_WRED);
  float*          bconst = (float*)(ws + OFF_BCONST);
  unsigned short* xibf   = (unsigned short*)(ws + OFF_XIBF);
  float*          bc     = (float*)(ws + OFF_BC);
  float*          hsb    = (float*)(ws + OFF_HS);
  int*            flags  = (int*)(ws + OFF_FLAGS);     // cnt1[64] | flag2[64]

  hipMemsetAsync(flags, 0, 2 * 64 * sizeof(int), stream);
  k_prep<<<6768, 256, 0, stream>>>(x, W_in, W_x, W_out, b_in, b_out,
                                   xbf, winbf, wxbf, woutbf, wrtbf, wred, bconst);
  k_wc<<<64, 256, 0, stream>>>(woutbf, wrtbf, wcbf);
  k_mega<<<1601, 256, 0, stream>>>(xbf, winbf, b_in, xibf, conv_w, conv_b,
                                   wxbf, b_x, bc, wcbf, bconst, out, dt, A, hsb,
                                   flags, flags + 64);
  k5_combine<<<2048, 256, 0, stream>>>(out, hsb, wred);
}